// Round 14
// baseline (157.165 us; speedup 1.0000x reference)
//
#include <hip/hip_runtime.h>
#include <hip/hip_bf16.h>
#include <stdint.h>

#define B_DIM   4096
#define IN_DIM  512
#define OUT_DIM 512
#define M_DIM   16
#define K_DIM   (IN_DIM * M_DIM)     // 8192
#define MN      (B_DIM * OUT_DIM)    // 2097152

// basis interpolation table: 256 intervals over [0.1, 10], stride 20 f32.
// tix*4B = e*80 + mh*32 — both multiples of 16 -> aligned f32x4 reads.
#define TBL_N    256
#define TBL_STR  20
#define TBL_F32  ((TBL_N + 1) * TBL_STR)   // 5140 floats = 20560 B
#define TBL_H    (9.9f / (float)TBL_N)
#define TBL_INVH ((float)TBL_N / 9.9f)

typedef unsigned short ushort_t;
typedef __attribute__((ext_vector_type(8))) __bf16 bf16x8;
typedef __attribute__((ext_vector_type(2))) __bf16 bf16x2;
typedef __attribute__((ext_vector_type(4))) float  f32x4;

__device__ __forceinline__ ushort_t f2bf(float f) {
  union { float f; uint32_t u; } v; v.f = f;
  uint32_t u = v.u + 0x7fffu + ((v.u >> 16) & 1u);   // RNE
  return (ushort_t)(u >> 16);
}

// pack two floats -> one u32 of 2 x bf16 (compiler emits v_cvt_pk_bf16_f32)
__device__ __forceinline__ uint32_t pkbf(float lo, float hi) {
  union { bf16x2 h; uint32_t u; } v;
  v.h[0] = (__bf16)lo; v.h[1] = (__bf16)hi;
  return v.u;
}

// ---------- phase 1: coeffs fp32 -> bf16  +  basis table build ----------
#define CONV_N4     (OUT_DIM * K_DIM / 4)
#define CONV_BLOCKS (CONV_N4 / 256)     // 4096
__global__ __launch_bounds__(256) void convert_coeffs_kernel(
    const float* __restrict__ src, ushort_t* __restrict__ dst,
    const float* __restrict__ bc, float* __restrict__ tG) {
  const int blk = blockIdx.x, tid = threadIdx.x;
  if (blk < CONV_BLOCKS) {
    int i = blk * 256 + tid;
    float4 v = ((const float4*)src)[i];
    ushort4 o;
    o.x = f2bf(v.x); o.y = f2bf(v.y); o.z = f2bf(v.z); o.w = f2bf(v.w);
    ((ushort4*)dst)[i] = o;
    return;
  }
  // table block: T[e][m] = f_m(0.1 + e*h) in full f32 (same math as r9..r12).
  const float LOG2E = 1.44269504088896340736f;
  const float LN2   = 0.69314718055994530942f;
  for (int e = tid; e <= TBL_N; e += 256) {
    float xv = 0.1f + (float)e * TBL_H;
    float xl2 = xv * LOG2E;
    float x2 = xv * xv, x3 = x2 * xv, x4 = x2 * x2;
    #pragma unroll
    for (int m = 0; m < M_DIM; ++m) {
      float b1 = bc[m*8+0], b2 = bc[m*8+1], b3 = bc[m*8+2], b4 = bc[m*8+3];
      float b5 = bc[m*8+4], b6 = bc[m*8+5], b7 = bc[m*8+6], b8 = bc[m*8+7];
      float e2    = __builtin_amdgcn_exp2f(b3 * xl2);
      float inner = e2 - 1.0f;                                  // expm1(b3 x) > 0
      float p     = __builtin_amdgcn_exp2f(b4 * __builtin_amdgcn_logf(inner));
      float L1    = __builtin_amdgcn_logf(1.0f + p);
      float vv    = __builtin_amdgcn_logf(1.0f + (b2 * LN2) * L1);
      float y = (b1 * LN2) * vv + b5 * xv + b6 * x2 + b7 * x3 + b8 * x4;
      tG[e * TBL_STR + m] = y;
    }
  }
}

// ---------- phase 2: FUSED GEMM, A-fragments computed IN REGISTERS ----------
// No As in LDS at all: for mfma_16x16x32, lane L's A-fragment is
// {row = wr*64 + t*16 + (L&15), i = (L>>4)>>1, m = ((L>>4)&1)*8 + 0..7}
// = ONE x-value + 8 consecutive m's = one table interpolation. The 4x
// wc-duplication costs only cheap interp VALU (r13: table BASIS = 12% VALU).
// Removes the ds_write + af ds_reads + the cross-wave As produce->consume
// serialization that survived every other fix (r7/r9/r13 post-mortems).
#define BM 128
#define BN 512
#define BK 32                 // = 2 input-columns x 16 m
#define SPLITK 8
#define KC (K_DIM / SPLITK)   // 1024
#define NITER (KC / BK)       // 32 K-steps
#define XCOLS (KC / M_DIM)    // 64 x-columns per block
#define XPAD  129             // Xs row-dim (128 rows + 1 pad)

#define GLD16(g, l) \
  __builtin_amdgcn_global_load_lds((const __attribute__((address_space(1))) void*)(g), \
                                   (__attribute__((address_space(3))) void*)(l), 16, 0, 0)

// fused counted-wait + barrier in ONE asm: memory ops cannot cross ("memory"
// clobber), register-only VALU/MFMA remain schedulable around it.
#define WAIT_BAR(N) \
  asm volatile("s_waitcnt vmcnt(" #N ") lgkmcnt(0)\n\ts_barrier" ::: "memory")

template <int ATOMIC>
__global__ __launch_bounds__(512, 2) void gemm_kernel(
    const float* __restrict__ x,      // [B_DIM][IN_DIM] fp32
    const ushort_t* __restrict__ Bt,  // coeffs bf16 [OUT_DIM][K_DIM]
    const float* __restrict__ tG,     // basis table [257][20] f32
    float* __restrict__ P) {          // partials [SPLITK][B][OUT] or out
  // LDS: Bs TRIBUF 96K + Xs 33.0K + Ts 20.1K = 148.8 KiB (1 block/CU)
  __shared__ __align__(16) ushort_t Bs[3][BN * BK];
  __shared__ __align__(16) float    Xs[XCOLS * XPAD];   // [col][row]
  __shared__ __align__(16) float    Ts[TBL_F32];
  const int tid  = threadIdx.x;
  const int wave = tid >> 6;
  const int lane = tid & 63;
  const int wgid = blockIdx.x;
  const int ks = wgid & 7, bm = wgid >> 3;   // same-ks blocks -> same XCD, B-slice L2-hot

  // ---- table -> LDS (one-time; 1285 float4s across 512 threads) ----
  {
    const float4* g4 = (const float4*)tG;
    float4* l4 = (float4*)Ts;
    for (int i = tid; i < TBL_F32 / 4; i += 512) l4[i] = g4[i];
  }
  // ---- x-tile -> LDS transposed (one-time, coalesced float4 loads) ----
  {
    const int r = tid >> 2, q = tid & 3;
    const float4* xrow = (const float4*)(x + (size_t)(bm * BM + r) * IN_DIM + ks * XCOLS);
    #pragma unroll
    for (int j = 0; j < 4; ++j) {
      float4 v = xrow[q * 4 + j];
      Xs[(q * 16 + j * 4 + 0) * XPAD + r] = v.x;
      Xs[(q * 16 + j * 4 + 1) * XPAD + r] = v.y;
      Xs[(q * 16 + j * 4 + 2) * XPAD + r] = v.z;
      Xs[(q * 16 + j * 4 + 3) * XPAD + r] = v.w;
    }
  }

  // ---- B staging: global_load_lds linear dest, pre-swizzled source slot ----
  const int srow = wave * 16 + (lane >> 2);
  const int scol = (((lane & 3) ^ ((lane >> 3) & 3)) * 8);
  const ushort_t* Bg0 = Bt + (size_t)srow * K_DIM + ks * KC + scol;
  const ushort_t* Bg1 = Bg0 + (size_t)128 * K_DIM;
  const ushort_t* Bg2 = Bg0 + (size_t)256 * K_DIM;
  const ushort_t* Bg3 = Bg0 + (size_t)384 * K_DIM;
  const int bofs0 = (wave * 16) * BK;
  const int bofs1 = (128 + wave * 16) * BK;
  const int bofs2 = (256 + wave * 16) * BK;
  const int bofs3 = (384 + wave * 16) * BK;

#define STAGEB(lb) do { \
    GLD16(Bg0, &Bs[lb][bofs0]); GLD16(Bg1, &Bs[lb][bofs1]); \
    GLD16(Bg2, &Bs[lb][bofs2]); GLD16(Bg3, &Bs[lb][bofs3]); \
    Bg0 += BK; Bg1 += BK; Bg2 += BK; Bg3 += BK; } while (0)

  // ---- MFMA geometry: 8 waves as 2x4 grid of 64x128 wave-tiles ----
  const int wr = wave >> 2, wc = wave & 3;
  const int fm = lane & 15;
  const int fkswz = (((lane >> 4) ^ ((lane >> 1) & 3)) << 3);
  // A-fragment decode for this lane:
  const int qq  = lane >> 4;          // k-slot
  const int iq  = qq >> 1;            // which of the 2 i-columns in this K-step
  const int mh8 = (qq & 1) * 8;       // m-half offset into table row (f32)
  const int arow0 = wr * 64 + fm;     // row of af[0]; af[t] row = arow0 + t*16

  f32x4 acc[4][8] = {};

  // in-register A-fragment: one Xs read + one table interp (4x f32x4) + pack.
#define MAKE_AF(dst, t) do { \
    float xv = Xs[(2 * (t) + iq) * XPAD + arow0 + 0]; \
    (void)0; \
    float uu = (xv - 0.1f) * TBL_INVH; \
    uu = fminf(fmaxf(uu, 0.0f), (float)TBL_N - 0.01f); \
    float fi = floorf(uu); \
    float fr = uu - fi; \
    int tix = (int)fi * TBL_STR + mh8; \
    f32x4 v0 = *(const f32x4*)&Ts[tix]; \
    f32x4 v1 = *(const f32x4*)&Ts[tix + 4]; \
    f32x4 w0 = *(const f32x4*)&Ts[tix + TBL_STR]; \
    f32x4 w1 = *(const f32x4*)&Ts[tix + TBL_STR + 4]; \
    uint32_t p0 = pkbf(v0[0] + fr * (w0[0] - v0[0]), v0[1] + fr * (w0[1] - v0[1])); \
    uint32_t p1 = pkbf(v0[2] + fr * (w0[2] - v0[2]), v0[3] + fr * (w0[3] - v0[3])); \
    uint32_t p2 = pkbf(v1[0] + fr * (w1[0] - v1[0]), v1[1] + fr * (w1[1] - v1[1])); \
    uint32_t p3 = pkbf(v1[2] + fr * (w1[2] - v1[2]), v1[3] + fr * (w1[3] - v1[3])); \
    union { uint32_t u[4]; bf16x8 h; } cvt_; \
    cvt_.u[0] = p0; cvt_.u[1] = p1; cvt_.u[2] = p2; cvt_.u[3] = p3; \
    dst = cvt_.h; \
  } while (0)

// NOTE: af[t] row = arow0 + t*16 — fold the +t*16 into the Xs index:
#undef MAKE_AF
#define MAKE_AF(dst, t) do { \
    float xv = Xs[(2 * (t)) * XPAD + iq * XPAD + arow0 + (t) * 16]; \
    float uu = (xv - 0.1f) * TBL_INVH; \
    uu = fminf(fmaxf(uu, 0.0f), (float)TBL_N - 0.01f); \
    float fi = floorf(uu); \
    float fr = uu - fi; \
    int tix = (int)fi * TBL_STR + mh8; \
    f32x4 v0 = *(const f32x4*)&Ts[tix]; \
    f32x4 v1 = *(const f32x4*)&Ts[tix + 4]; \
    f32x4 w0 = *(const f32x4*)&Ts[tix + TBL_STR]; \
    f32x4 w1 = *(const f32x4*)&Ts[tix + TBL_STR + 4]; \
    uint32_t p0 = pkbf(v0[0] + fr * (w0[0] - v0[0]), v0[1] + fr * (w0[1] - v0[1])); \
    uint32_t p1 = pkbf(v0[2] + fr * (w0[2] - v0[2]), v0[3] + fr * (w0[3] - v0[3])); \
    uint32_t p2 = pkbf(v1[0] + fr * (w1[0] - v1[0]), v1[1] + fr * (w1[1] - v1[1])); \
    uint32_t p3 = pkbf(v1[2] + fr * (w1[2] - v1[2]), v1[3] + fr * (w1[3] - v1[3])); \
    union { uint32_t u[4]; bf16x8 h; } cvt_; \
    cvt_.u[0] = p0; cvt_.u[1] = p1; cvt_.u[2] = p2; cvt_.u[3] = p3; \
    dst = cvt_.h; \
  } while (0)

#define COMPUTE(lb, t) do { \
    bf16x8 af[4], bfv[8]; \
    MAKE_AF(af[0], t); MAKE_AF(af[1], t); /* placeholder, fixed below */ \
  } while (0)
#undef COMPUTE
#define COMPUTE(lb, t) do { \
    bf16x8 af0, af1, af2, af3, bfv[8]; \
    MAKE_AF(af0, t); \
    { bf16x8 tmp_; MAKE_AF(tmp_, t); af1 = tmp_; } \
  } while (0)
#undef COMPUTE
  // (clean version: af row差 handled inside MAKE_AF via the t*16 term; the four
  // fragments differ only in their Xs row — call MAKE_AF_R with explicit row.)
#undef MAKE_AF
#define MAKE_AF_R(dst, t, rofs) do { \
    float xv = Xs[(2 * (t) + iq) * XPAD + arow0 + (rofs)]; \
    float uu = (xv - 0.1f) * TBL_INVH; \
    uu = fminf(fmaxf(uu, 0.0f), (float)TBL_N - 0.01f); \
    float fi = floorf(uu); \
    float fr = uu - fi; \
    int tix = (int)fi * TBL_STR + mh8; \
    f32x4 v0 = *(const f32x4*)&Ts[tix]; \
    f32x4 v1 = *(const f32x4*)&Ts[tix + 4]; \
    f32x4 w0 = *(const f32x4*)&Ts[tix + TBL_STR]; \
    f32x4 w1 = *(const f32x4*)&Ts[tix + TBL_STR + 4]; \
    union { uint32_t u[4]; bf16x8 h; } cvt_; \
    cvt_.u[0] = pkbf(v0[0] + fr * (w0[0] - v0[0]), v0[1] + fr * (w0[1] - v0[1])); \
    cvt_.u[1] = pkbf(v0[2] + fr * (w0[2] - v0[2]), v0[3] + fr * (w0[3] - v0[3])); \
    cvt_.u[2] = pkbf(v1[0] + fr * (w1[0] - v1[0]), v1[1] + fr * (w1[1] - v1[1])); \
    cvt_.u[3] = pkbf(v1[2] + fr * (w1[2] - v1[2]), v1[3] + fr * (w1[3] - v1[3])); \
    dst = cvt_.h; \
  } while (0)

#define COMPUTE2(lb, t) do { \
    bf16x8 af[4], bfv[8]; \
    MAKE_AF_R(af[0], t, 0);  MAKE_AF_R(af[1], t, 16); \
    MAKE_AF_R(af[2], t, 32); MAKE_AF_R(af[3], t, 48); \
    _Pragma("unroll") \
    for (int u = 0; u < 8; ++u) \
      bfv[u] = *(const bf16x8*)&Bs[lb][(wc * 128 + u * 16 + fm) * BK + fkswz]; \
    __builtin_amdgcn_s_setprio(1); \
    _Pragma("unroll") \
    for (int mt = 0; mt < 4; ++mt) \
      _Pragma("unroll") \
      for (int nt = 0; nt < 8; ++nt) \
        acc[mt][nt] = __builtin_amdgcn_mfma_f32_16x16x32_bf16(af[mt], bfv[nt], acc[mt][nt], 0, 0, 0); \
    __builtin_amdgcn_s_setprio(0); \
  } while (0)

  // one step: stage batch t+2, compute tile t from Bs[t%3] + in-reg A.
  // vmcnt induction: before wait, outstanding = batch t+1 (4) + batch t+2 (4);
  // vmcnt(4) retires batch t+1 exactly -> next step's Bs ready. (t=0: prologue
  // drained; only batch 2 outstanding; wait passes, batch 1 already resident.)
#define STEP(lbN, lb, t) do { \
    STAGEB(lbN); COMPUTE2(lb, t); WAIT_BAR(4); } while (0)

  // ---- prologue: Ts + Xs + first two B batches, one full drain ----
  STAGEB(0); STAGEB(1);
  __syncthreads();
  // ---- main loop: 30 steps, statically unrolled x6 (lb period 3) ----
  for (int tb = 0; tb < NITER - 2; tb += 6) {
    STEP(2, 0, tb + 0);
    STEP(0, 1, tb + 1);
    STEP(1, 2, tb + 2);
    STEP(2, 0, tb + 3);
    STEP(0, 1, tb + 4);
    STEP(1, 2, tb + 5);
  }
  // ---- tail K-steps: t = 30, 31 (all batches staged) ----
  COMPUTE2(0, 30);              // 30%3 = 0
  WAIT_BAR(0);
  COMPUTE2(1, 31);              // 31%3 = 1

  // ---- epilogue: C/D layout col = lane&15, row = (lane>>4)*4 + reg ----
  const int colb = wc * 128 + fm;
  const int rowb = bm * BM + wr * 64 + (lane >> 4) * 4;
  float* out = P + (ATOMIC ? (size_t)0 : (size_t)ks * MN);
  #pragma unroll
  for (int mt = 0; mt < 4; ++mt) {
    #pragma unroll
    for (int nt = 0; nt < 8; ++nt) {
      #pragma unroll
      for (int j = 0; j < 4; ++j) {
        int row = rowb + mt * 16 + j;
        int col = colb + nt * 16;
        float vv = acc[mt][nt][j];
        if (ATOMIC) atomicAdd(out + (size_t)row * OUT_DIM + col, vv);
        else        out[(size_t)row * OUT_DIM + col] = vv;
      }
    }
  }
#undef STAGEB
#undef MAKE_AF_R
#undef COMPUTE2
#undef STEP
}

// ---------- phase 3: reduce split-K partials ----------
__global__ __launch_bounds__(256) void reduce_kernel(
    const float* __restrict__ P, float* __restrict__ out) {
  int i = blockIdx.x * 256 + threadIdx.x;
  const float4* p = (const float4*)P;
  float4 r = p[i];
  #pragma unroll
  for (int s = 1; s < SPLITK; ++s) {
    float4 v = p[i + (size_t)s * (MN / 4)];
    r.x += v.x; r.y += v.y; r.z += v.z; r.w += v.w;
  }
  ((float4*)out)[i] = r;
}

extern "C" void kernel_launch(void* const* d_in, const int* in_sizes, int n_in,
                              void* d_out, int out_size, void* d_ws, size_t ws_size,
                              hipStream_t stream) {
  const float* x      = (const float*)d_in[0];   // [4096][512]
  const float* coeffs = (const float*)d_in[1];   // [512][512][16]
  const float* b_coef = (const float*)d_in[2];   // [16][8]
  float* out = (float*)d_out;
  char*  ws  = (char*)d_ws;

  const size_t COEF_BYTES = (size_t)OUT_DIM * K_DIM * 2;   // 8 MiB
  const size_t TBL_BYTES  = (size_t)TBL_F32 * 4;           // 20560 B (16-mult)
  ushort_t* coefb = (ushort_t*)ws;
  float*    tG    = (float*)(ws + COEF_BYTES);
  float* partials = (float*)(ws + COEF_BYTES + TBL_BYTES);
  const size_t FULL = COEF_BYTES + TBL_BYTES + (size_t)SPLITK * MN * 4;
  const bool use_atomic = (ws_size < FULL);   // deterministic per-session branch

  convert_coeffs_kernel<<<CONV_BLOCKS + 1, 256, 0, stream>>>(coeffs, coefb, b_coef, tG);

  const int nblk = (B_DIM / BM) * SPLITK;   // 32 x 8 = 256 blocks, 1/CU
  if (use_atomic) {
    hipMemsetAsync(d_out, 0, (size_t)MN * 4, stream);
    gemm_kernel<1><<<nblk, 512, 0, stream>>>(x, coefb, tG, out);
  } else {
    gemm_kernel<0><<<nblk, 512, 0, stream>>>(x, coefb, tG, partials);
    reduce_kernel<<<MN / 4 / 256, 256, 0, stream>>>(partials, out);
  }
}

// Round 15
// 137.035 us; speedup vs baseline: 1.1469x; 1.1469x over previous
//
#include <hip/hip_runtime.h>
#include <hip/hip_bf16.h>
#include <stdint.h>

#define B_DIM   4096
#define IN_DIM  512
#define OUT_DIM 512
#define M_DIM   16
#define K_DIM   (IN_DIM * M_DIM)     // 8192
#define MN      (B_DIM * OUT_DIM)    // 2097152

typedef unsigned short ushort_t;
typedef __attribute__((ext_vector_type(8))) __bf16 bf16x8;
typedef __attribute__((ext_vector_type(2))) __bf16 bf16x2;
typedef __attribute__((ext_vector_type(4))) float  f32x4;

__device__ __forceinline__ ushort_t f2bf(float f) {
  union { float f; uint32_t u; } v; v.f = f;
  uint32_t u = v.u + 0x7fffu + ((v.u >> 16) & 1u);   // RNE
  return (ushort_t)(u >> 16);
}

// pack two floats -> one u32 of 2 x bf16 (compiler emits v_cvt_pk_bf16_f32)
__device__ __forceinline__ uint32_t pkbf(float lo, float hi) {
  union { bf16x2 h; uint32_t u; } v;
  v.h[0] = (__bf16)lo; v.h[1] = (__bf16)hi;
  return v.u;
}

// force a wave-uniform float into an SGPR
__device__ __forceinline__ float rfl(float f) {
  union { float f; int i; } v; v.f = f;
  v.i = __builtin_amdgcn_readfirstlane(v.i);
  return v.f;
}

// ---------- phase 1: coeffs fp32 -> bf16 (layout [OUT][IN][M] == B^T [N][K]) ----------
#define CONV_N4 (OUT_DIM * K_DIM / 4)
__global__ __launch_bounds__(256) void convert_coeffs_kernel(
    const float* __restrict__ src, ushort_t* __restrict__ dst) {
  int i = blockIdx.x * 256 + threadIdx.x;
  float4 v = ((const float4*)src)[i];
  ushort4 o;
  o.x = f2bf(v.x); o.y = f2bf(v.y); o.z = f2bf(v.z); o.w = f2bf(v.w);
  ((ushort4*)dst)[i] = o;
}

// ---------- phase 2: FUSED basis+GEMM (r9 core), lane-contiguous partial store ----------
#define BM 128
#define BN 512
#define BK 32                 // = 2 input-columns x 16 m
#define SPLITK 8
#define KC (K_DIM / SPLITK)   // 1024
#define NITER (KC / BK)       // 32 K-steps
#define XCOLS (KC / M_DIM)    // 64 x-columns per block
#define XPAD  129             // row-dim pad for conflict-free reads

#define GLD16(g, l) \
  __builtin_amdgcn_global_load_lds((const __attribute__((address_space(1))) void*)(g), \
                                   (__attribute__((address_space(3))) void*)(l), 16, 0, 0)

// fused counted-wait + barrier in ONE asm: memory ops cannot cross ("memory"
// clobber), register-only VALU/MFMA remain schedulable around it.
#define WAIT_BAR(N) \
  asm volatile("s_waitcnt vmcnt(" #N ") lgkmcnt(0)\n\ts_barrier" ::: "memory")

template <int ATOMIC>
__global__ __launch_bounds__(512, 2) void gemm_kernel(
    const float* __restrict__ x,      // [B_DIM][IN_DIM] fp32
    const ushort_t* __restrict__ Bt,  // coeffs bf16 [OUT_DIM][K_DIM]
    const float* __restrict__ bc,     // [16][8]
    float* __restrict__ P) {          // permuted partials [SPLITK][...] or out
  // LDS: As dbuf 16K + Bs TRIBUF 96K + Xs 32.25K = 144.25 KiB (1 block/CU)
  __shared__ __align__(16) ushort_t As[2][BM * BK];
  __shared__ __align__(16) ushort_t Bs[3][BN * BK];
  __shared__ __align__(16) float    Xs[XCOLS * XPAD];
  const int tid  = threadIdx.x;
  const int wave = tid >> 6;
  const int lane = tid & 63;
  const int wgid = blockIdx.x;
  const int ks = wgid & 7, bm = wgid >> 3;   // same-ks blocks -> same XCD, B-slice L2-hot

  // ---- x-tile staging (one-time): coalesced float4 loads -> transposed LDS ----
  {
    const int r = tid >> 2, q = tid & 3;
    const float4* xrow = (const float4*)(x + (size_t)(bm * BM + r) * IN_DIM + ks * XCOLS);
    #pragma unroll
    for (int j = 0; j < 4; ++j) {
      float4 v = xrow[q * 4 + j];
      Xs[(q * 16 + j * 4 + 0) * XPAD + r] = v.x;
      Xs[(q * 16 + j * 4 + 1) * XPAD + r] = v.y;
      Xs[(q * 16 + j * 4 + 2) * XPAD + r] = v.z;
      Xs[(q * 16 + j * 4 + 3) * XPAD + r] = v.w;
    }
  }

  // ---- B staging: global_load_lds linear dest, pre-swizzled source slot ----
  const int srow = wave * 16 + (lane >> 2);
  const int scol = (((lane & 3) ^ ((lane >> 3) & 3)) * 8);
  const ushort_t* Bg0 = Bt + (size_t)srow * K_DIM + ks * KC + scol;
  const ushort_t* Bg1 = Bg0 + (size_t)128 * K_DIM;
  const ushort_t* Bg2 = Bg0 + (size_t)256 * K_DIM;
  const ushort_t* Bg3 = Bg0 + (size_t)384 * K_DIM;
  const int bofs0 = (wave * 16) * BK;
  const int bofs1 = (128 + wave * 16) * BK;
  const int bofs2 = (256 + wave * 16) * BK;
  const int bofs3 = (384 + wave * 16) * BK;

#define STAGEB(lb) do { \
    GLD16(Bg0, &Bs[lb][bofs0]); GLD16(Bg1, &Bs[lb][bofs1]); \
    GLD16(Bg2, &Bs[lb][bofs2]); GLD16(Bg3, &Bs[lb][bofs3]); \
    Bg0 += BK; Bg1 += BK; Bg2 += BK; Bg3 += BK; } while (0)

  // ---- basis production: thread -> (row, i_local, m-half), half wave-uniform ----
  const int half = wave & 1;                       // m in [half*8, half*8+8)
  const int arow = (wave >> 1) * 32 + (lane >> 1); // 0..127
  const int il   = lane & 1;                       // which of 2 input cols in BK
  const int aslot = ((il * 2 + half) ^ ((lane >> 2) & 3));  // XOR-swizzled 16B slot
  const int awe   = arow * BK + aslot * 8;
  const int xbase = il * XPAD + arow;              // Xs[(il+2t)*XPAD + arow]

  const float LOG2E = 1.44269504088896340736f;
  const float LN2   = 0.69314718055994530942f;
  // c1,c2 pre-scaled by LN2; kept SGPR via re-readfirstlane
  float c1[8], c2[8], c3[8], c4[8], c5[8], c6[8], c7[8], c8[8];
  {
    const float* bch = bc + half * 64;
    #pragma unroll
    for (int m = 0; m < 8; ++m) {
      c1[m] = rfl(rfl(bch[m*8+0]) * LN2); c2[m] = rfl(rfl(bch[m*8+1]) * LN2);
      c3[m] = rfl(bch[m*8+2]); c4[m] = rfl(bch[m*8+3]);
      c5[m] = rfl(bch[m*8+4]); c6[m] = rfl(bch[m*8+5]);
      c7[m] = rfl(bch[m*8+6]); c8[m] = rfl(bch[m*8+7]);
    }
  }

#define BASIS(ab, t) do { \
    float xv = Xs[xbase + 2 * XPAD * (t)]; \
    float xl2 = xv * LOG2E; \
    float x2 = xv * xv, x3 = x2 * xv, x4 = x2 * x2; \
    float ym[8]; \
    _Pragma("unroll") \
    for (int mi = 0; mi < 8; ++mi) { \
      float e     = __builtin_amdgcn_exp2f(c3[mi] * xl2); \
      float inner = e - 1.0f; \
      float p     = __builtin_amdgcn_exp2f(c4[mi] * __builtin_amdgcn_logf(inner)); \
      float L1    = __builtin_amdgcn_logf(1.0f + p); \
      float vv    = __builtin_amdgcn_logf(1.0f + c2[mi] * L1); \
      ym[mi] = c1[mi] * vv + c5[mi] * xv + c6[mi] * x2 + c7[mi] * x3 + c8[mi] * x4; \
    } \
    *(uint4*)(&As[ab][awe]) = make_uint4(pkbf(ym[0], ym[1]), pkbf(ym[2], ym[3]), \
                                         pkbf(ym[4], ym[5]), pkbf(ym[6], ym[7])); \
  } while (0)

  // ---- MFMA geometry: 8 waves as 2x4 grid of 64x128 wave-tiles ----
  const int wr = wave >> 2, wc = wave & 3;
  const int fm = lane & 15;
  const int fkswz = (((lane >> 4) ^ ((lane >> 1) & 3)) << 3);

  f32x4 acc[4][8] = {};

#define COMPUTE(ab, lb) do { \
    bf16x8 af[4], bfv[8]; \
    _Pragma("unroll") \
    for (int t2 = 0; t2 < 4; ++t2) \
      af[t2] = *(const bf16x8*)&As[ab][(wr * 64 + t2 * 16 + fm) * BK + fkswz]; \
    _Pragma("unroll") \
    for (int u = 0; u < 8; ++u) \
      bfv[u] = *(const bf16x8*)&Bs[lb][(wc * 128 + u * 16 + fm) * BK + fkswz]; \
    __builtin_amdgcn_s_setprio(1); \
    _Pragma("unroll") \
    for (int mt = 0; mt < 4; ++mt) \
      _Pragma("unroll") \
      for (int nt = 0; nt < 8; ++nt) \
        acc[mt][nt] = __builtin_amdgcn_mfma_f32_16x16x32_bf16(af[mt], bfv[nt], acc[mt][nt], 0, 0, 0); \
    __builtin_amdgcn_s_setprio(0); \
  } while (0)

#define STEP(lbN, ap, ac, lb, t1) do { \
    STAGEB(lbN); BASIS(ap, t1); COMPUTE(ac, lb); WAIT_BAR(4); } while (0)

  // ---- prologue ----
  STAGEB(0); STAGEB(1);
  __syncthreads();              // Xs + Bs[0..1] visible (full drain, once)
  BASIS(0, 0);
  WAIT_BAR(0);                  // As[0] visible

  // ---- main loop: 30 steps, statically unrolled x6 (lb period 3, As parity 2) ----
  for (int tb = 0; tb < NITER - 2; tb += 6) {
    STEP(2, 1, 0, 0, tb + 1);   // t = tb+0
    STEP(0, 0, 1, 1, tb + 2);   // t = tb+1
    STEP(1, 1, 0, 2, tb + 3);   // t = tb+2
    STEP(2, 0, 1, 0, tb + 4);   // t = tb+3
    STEP(0, 1, 0, 1, tb + 5);   // t = tb+4
    STEP(1, 0, 1, 2, tb + 6);   // t = tb+5
  }
  // ---- tail K-steps: t = 30, 31 (all 32 batches already staged) ----
  BASIS(1, NITER - 1);
  COMPUTE(0, 0);                // t=30: As[0], Bs[30%3=0]
  WAIT_BAR(0);
  COMPUTE(1, 1);                // t=31: As[1], Bs[31%3=1]

  // ---- C-write ----
  if (ATOMIC) {
    // fallback path unchanged: scatter atomics into row-major out
    const int colb = wc * 128 + fm;
    const int rowb = bm * BM + wr * 64 + (lane >> 4) * 4;
    #pragma unroll
    for (int mt = 0; mt < 4; ++mt)
      #pragma unroll
      for (int nt = 0; nt < 8; ++nt)
        #pragma unroll
        for (int j = 0; j < 4; ++j)
          atomicAdd(P + (size_t)(rowb + mt * 16 + j) * OUT_DIM + (colb + nt * 16),
                    acc[mt][nt][j]);
  } else {
    // lane-contiguous PERMUTED partial store: each wave-instruction writes
    // 64 lanes x 16B = 1KB fully coalesced (was 128 scattered dwords/thread
    // in 64B HBM granules — the ~21-25us epilogue tail, r14 post-mortem).
    // Layout (f32): P[ks*MN + bm*65536 + wave*8192 + (mt*8+nt)*256 + lane*4 + j]
    float* dst = P + (size_t)ks * MN + (size_t)bm * (BM * BN)
                   + wave * 8192 + lane * 4;
    #pragma unroll
    for (int mt = 0; mt < 4; ++mt)
      #pragma unroll
      for (int nt = 0; nt < 8; ++nt)
        *(f32x4*)(dst + (mt * 8 + nt) * 256) = acc[mt][nt];
  }
#undef STAGEB
#undef BASIS
#undef COMPUTE
#undef STEP
}

// ---------- phase 3: reduce permuted split-K partials -> row-major out ----------
// Same s=0..7 sum order as always (bitwise identical result); the permutation
// decode moves the scatter to the final 8 MB write instead of the 64 MB one.
__global__ __launch_bounds__(256) void reduce_kernel(
    const float* __restrict__ P, float* __restrict__ out) {
  int i = blockIdx.x * 256 + threadIdx.x;   // float4 index within one slab
  const float4* p = (const float4*)P;
  float4 r = p[i];
  #pragma unroll
  for (int s = 1; s < SPLITK; ++s) {
    float4 v = p[i + (size_t)s * (MN / 4)];
    r.x += v.x; r.y += v.y; r.z += v.z; r.w += v.w;
  }
  // decode permuted slot -> (row, col): i = bm*16384 + wave*2048 + (mt*8+nt)*64 + lane
  int bm   = i >> 14;
  int rem  = i & 16383;
  int wv   = rem >> 11;
  int rem2 = rem & 2047;
  int mtnt = rem2 >> 6;
  int lane = rem2 & 63;
  int mt = mtnt >> 3, nt = mtnt & 7;
  int wr = wv >> 2,  wc = wv & 3;
  int row = bm * BM + wr * 64 + mt * 16 + (lane >> 4) * 4;
  int col = wc * 128 + nt * 16 + (lane & 15);
  float* o = out + (size_t)row * OUT_DIM + col;
  o[0 * OUT_DIM] = r.x;
  o[1 * OUT_DIM] = r.y;
  o[2 * OUT_DIM] = r.z;
  o[3 * OUT_DIM] = r.w;
}

extern "C" void kernel_launch(void* const* d_in, const int* in_sizes, int n_in,
                              void* d_out, int out_size, void* d_ws, size_t ws_size,
                              hipStream_t stream) {
  const float* x      = (const float*)d_in[0];   // [4096][512]
  const float* coeffs = (const float*)d_in[1];   // [512][512][16]
  const float* b_coef = (const float*)d_in[2];   // [16][8]
  float* out = (float*)d_out;
  char*  ws  = (char*)d_ws;

  const size_t COEF_BYTES = (size_t)OUT_DIM * K_DIM * 2;   // 8 MiB
  ushort_t* coefb = (ushort_t*)ws;
  float* partials = (float*)(ws + COEF_BYTES);
  const size_t FULL = COEF_BYTES + (size_t)SPLITK * MN * 4;  // 72 MiB
  const bool use_atomic = (ws_size < FULL);   // deterministic per-session branch

  convert_coeffs_kernel<<<CONV_N4 / 256, 256, 0, stream>>>(coeffs, coefb);

  const int nblk = (B_DIM / BM) * SPLITK;   // 32 x 8 = 256 blocks, 1/CU
  if (use_atomic) {
    hipMemsetAsync(d_out, 0, (size_t)MN * 4, stream);
    gemm_kernel<1><<<nblk, 512, 0, stream>>>(x, coefb, b_coef, out);
  } else {
    gemm_kernel<0><<<nblk, 512, 0, stream>>>(x, coefb, b_coef, partials);
    reduce_kernel<<<MN / 4 / 256, 256, 0, stream>>>(partials, out);
  }
}